// Round 12
// baseline (371.145 us; speedup 1.0000x reference)
//
#include <hip/hip_runtime.h>
#include <math.h>

constexpr int HID = 1024;
constexpr float NEG_SLOPE = 0.2f;
constexpr float EPSV = 1e-16f;

typedef __bf16 bf16x8 __attribute__((ext_vector_type(8)));
typedef float f32x4 __attribute__((ext_vector_type(4)));
typedef float f32x2 __attribute__((ext_vector_type(2)));
typedef unsigned short us8 __attribute__((ext_vector_type(8)));
typedef unsigned short us4 __attribute__((ext_vector_type(4)));
typedef unsigned short ushort_t;

#define AS1 __attribute__((address_space(1)))
#define AS3 __attribute__((address_space(3)))

__device__ __forceinline__ float4 ld4(const float* p){ return *reinterpret_cast<const float4*>(p); }
__device__ __forceinline__ float b2f(ushort_t u){ return __uint_as_float(((unsigned)u) << 16); }
__device__ __forceinline__ ushort_t f2b(float f){
  unsigned u = __float_as_uint(f);
  return (ushort_t)((u + 0x7FFFu + ((u >> 16) & 1u)) >> 16);
}
__device__ __forceinline__ float rfl(float x){
  return __uint_as_float(__builtin_amdgcn_readfirstlane(__float_as_uint(x)));
}
__device__ __forceinline__ f32x2 up2(unsigned u){
  f32x2 r;
  r[0] = __uint_as_float(u << 16);
  r[1] = __uint_as_float(u & 0xffff0000u);
  return r;
}
__device__ __forceinline__ f32x2 lrelu2(f32x2 v){
  return __builtin_elementwise_max(v, v * NEG_SLOPE);
}

// ---------------- batched weight transpose + f32->bf16 (five 1024x1024 mats) ----------------
struct TP5 { const float* src[5]; ushort_t* dst[5]; };
__global__ __launch_bounds__(256) void transpose_f2b_5(TP5 p){
  const int z = blockIdx.z;
  const float* W = p.src[z];
  ushort_t* WT = p.dst[z];
  __shared__ float tile[32][33];
  const int tx = threadIdx.x & 31, ty = threadIdx.x >> 5;
  const int n0 = blockIdx.x * 32, k0 = blockIdx.y * 32;
  #pragma unroll
  for (int r = 0; r < 32; r += 8)
    tile[ty + r][tx] = W[(size_t)(k0 + ty + r) * 1024 + n0 + tx];
  __syncthreads();
  #pragma unroll
  for (int r = 0; r < 32; r += 8)
    WT[(size_t)(n0 + ty + r) * 1024 + k0 + tx] = f2b(tile[tx][ty + r]);
}

// ---------------- single transpose (for m1/m2) ----------------
__global__ __launch_bounds__(256) void transpose_f2b(const float* __restrict__ W, ushort_t* __restrict__ WT,
                                                     int K, int N){
  __shared__ float tile[32][33];
  const int tx = threadIdx.x & 31, ty = threadIdx.x >> 5;
  const int n0 = blockIdx.x * 32, k0 = blockIdx.y * 32;
  #pragma unroll
  for (int r = 0; r < 32; r += 8)
    tile[ty + r][tx] = W[(size_t)(k0 + ty + r) * N + n0 + tx];
  __syncthreads();
  #pragma unroll
  for (int r = 0; r < 32; r += 8)
    WT[(size_t)(n0 + ty + r) * K + k0 + tx] = f2b(tile[tx][ty + r]);
}

// ---------------- bias concat (4 x 1024 f32) ----------------
struct BC4 { const float* s[4]; };
__global__ void concat_bias(BC4 p, float* __restrict__ dst){
  const int i = blockIdx.x * blockDim.x + threadIdx.x;   // 4096 total
  dst[i] = p.s[i >> 10][i & 1023];
}

// ---------------- f32 -> bf16 elementwise ----------------
__global__ void convert_f2b(const float* __restrict__ in, ushort_t* __restrict__ out, size_t n){
  size_t i = ((size_t)blockIdx.x * blockDim.x + threadIdx.x) * 4;
  const size_t stride = (size_t)gridDim.x * blockDim.x * 4;
  for (; i < n; i += stride){
    const float4 v = ld4(in + i);
    us4 o = {f2b(v.x), f2b(v.y), f2b(v.z), f2b(v.w)};
    *reinterpret_cast<us4*>(out + i) = o;
  }
}

// ---------------- bf16 MFMA GEMM, 128x128 tile, BK=64, 8 waves (32x64 each) ----------------
// (frozen since r9) 2-phase dbuf LDS + T2 XOR swizzle + coalesced us8 epilogue.
template<int ACT, int OUTB>
__global__ __launch_bounds__(512, 4) void gemm_mfma(
    const ushort_t* __restrict__ A, const ushort_t* __restrict__ BT,
    const float* __restrict__ bias, float* __restrict__ Cf, ushort_t* __restrict__ Cb,
    int M, int K, int N)
{
  __shared__ __align__(16) char smem[65536];
  ushort_t* Asl = (ushort_t*)smem;
  ushort_t* Bsl = (ushort_t*)(smem + 32768);
  const int tid = threadIdx.x;
  const int lane = tid & 63, wave = tid >> 6;
  const int wr = (wave >> 1) * 32;
  const int wc = (wave & 1) * 64;

  const int nwg = gridDim.x * gridDim.y;
  int wg = blockIdx.y * gridDim.x + blockIdx.x;
  {
    const int q = nwg >> 3, r = nwg & 7;
    const int xcd = wg & 7, lo = wg >> 3;
    wg = (xcd < r ? xcd * (q + 1) : r * (q + 1) + (xcd - r) * q) + lo;
  }
  const int bm = (wg / gridDim.x) * 128, bn = (wg % gridDim.x) * 128;

  const int mrow = lane & 15;
  const int r0 = (lane >> 4) * 4;

  f32x4 acc[2][4];
  #pragma unroll
  for (int i = 0; i < 2; ++i)
    #pragma unroll
    for (int j = 0; j < 4; ++j)
      acc[i][j] = (f32x4){0.f, 0.f, 0.f, 0.f};

  const int srow = tid >> 3;
  const int ssl = (((lane & 7) ^ (lane >> 3))) * 8;
  const int ldst = wave * 512 + lane * 8;

  auto stage = [&](int buf, int k0){
    #pragma unroll
    for (int q = 0; q < 2; ++q){
      const int row = q * 64 + srow;
      int arow = bm + row; if (arow > M - 1) arow = M - 1;
      __builtin_amdgcn_global_load_lds(
        (const AS1 unsigned int*)(A + (size_t)arow * K + k0 + ssl),
        (AS3 unsigned int*)(Asl + buf * 8192 + q * 4096 + ldst), 16, 0, 0);
      __builtin_amdgcn_global_load_lds(
        (const AS1 unsigned int*)(BT + (size_t)(bn + row) * K + k0 + ssl),
        (AS3 unsigned int*)(Bsl + buf * 8192 + q * 4096 + ldst), 16, 0, 0);
    }
  };

  const int kslice = (lane >> 4);
  auto compute = [&](int buf){
    #pragma unroll
    for (int ks = 0; ks < 2; ++ks){
      bf16x8 af[2], bfr[4];
      #pragma unroll
      for (int i = 0; i < 2; ++i){
        const int row = wr + i * 16 + mrow;
        const int sl = (ks * 4 + kslice) ^ (row & 7);
        af[i] = *reinterpret_cast<const bf16x8*>(&Asl[buf * 8192 + row * 64 + sl * 8]);
      }
      #pragma unroll
      for (int j = 0; j < 4; ++j){
        const int row = wc + j * 16 + mrow;
        const int sl = (ks * 4 + kslice) ^ (row & 7);
        bfr[j] = *reinterpret_cast<const bf16x8*>(&Bsl[buf * 8192 + row * 64 + sl * 8]);
      }
      #pragma unroll
      for (int i = 0; i < 2; ++i)
        #pragma unroll
        for (int j = 0; j < 4; ++j)
          acc[i][j] = __builtin_amdgcn_mfma_f32_16x16x32_bf16(af[i], bfr[j], acc[i][j], 0, 0, 0);
    }
  };

  stage(0, 0);
  asm volatile("s_waitcnt vmcnt(0)" ::: "memory");
  __builtin_amdgcn_s_barrier();

  const int NT = K >> 6;
  int cur = 0;
  for (int t = 0; t < NT; ++t){
    if (t + 1 < NT) stage(cur ^ 1, (t + 1) << 6);
    compute(cur);
    asm volatile("s_waitcnt vmcnt(0)" ::: "memory");
    __builtin_amdgcn_s_barrier();
    cur ^= 1;
  }

  float* ldsF = (float*)smem;
  const int wbase = wave * 2048;
  #pragma unroll
  for (int i = 0; i < 2; ++i)
    #pragma unroll
    for (int j = 0; j < 4; ++j)
      #pragma unroll
      for (int r = 0; r < 4; ++r)
        ldsF[wbase + (i * 16 + r0 + r) * 64 + j * 16 + mrow] = acc[i][j][r];
  asm volatile("s_waitcnt lgkmcnt(0)" ::: "memory");

  const int lrow = lane >> 3, lcol = (lane & 7) * 8;
  #pragma unroll
  for (int i2 = 0; i2 < 4; ++i2){
    const int row = bm + wr + i2 * 8 + lrow;
    const int col = bn + wc + lcol;
    if (row < M){
      const f32x4 lo = *reinterpret_cast<const f32x4*>(&ldsF[wbase + (i2 * 8 + lrow) * 64 + lcol]);
      const f32x4 hi = *reinterpret_cast<const f32x4*>(&ldsF[wbase + (i2 * 8 + lrow) * 64 + lcol + 4]);
      const float4 b0 = ld4(bias + col), b1 = ld4(bias + col + 4);
      float v[8] = {lo[0] + b0.x, lo[1] + b0.y, lo[2] + b0.z, lo[3] + b0.w,
                    hi[0] + b1.x, hi[1] + b1.y, hi[2] + b1.z, hi[3] + b1.w};
      #pragma unroll
      for (int u = 0; u < 8; ++u){
        float t2 = v[u];
        if (ACT == 1) t2 = fmaxf(t2, 0.f);
        else if (ACT == 2) t2 = (t2 > 0.f) ? t2 : expm1f(t2);
        v[u] = t2;
      }
      if (OUTB){
        us8 ov;
        #pragma unroll
        for (int u = 0; u < 8; ++u) ov[u] = f2b(v[u]);
        *reinterpret_cast<us8*>(Cb + (size_t)row * N + col) = ov;
      } else {
        *reinterpret_cast<float4*>(Cf + (size_t)row * N + col)     = make_float4(v[0], v[1], v[2], v[3]);
        *reinterpret_cast<float4*>(Cf + (size_t)row * N + col + 4) = make_float4(v[4], v[5], v[6], v[7]);
      }
    }
  }
}

// ---------------- bf16 MFMA GEMM, 256x256 tile, BK=64, 8 waves (128x64 each) ----------------
// Same 2-phase/T2 structure as gemm_mfma, but 2x LDS-read reuse (12 reads / 32 MFMA).
// 128 KB LDS double-buffer, 1 block/CU. Used for the large N=2048 GEMMs.
template<int ACT, int OUTB>
__global__ __launch_bounds__(512, 2) void gemm_mfma256(
    const ushort_t* __restrict__ A, const ushort_t* __restrict__ BT,
    const float* __restrict__ bias, float* __restrict__ Cf, ushort_t* __restrict__ Cb,
    int M, int K, int N)
{
  __shared__ __align__(16) char smem[131072];
  ushort_t* Asl = (ushort_t*)smem;              // [2][16384]
  ushort_t* Bsl = (ushort_t*)(smem + 65536);    // [2][16384]
  const int tid = threadIdx.x;
  const int lane = tid & 63, wave = tid >> 6;   // 8 waves
  const int wr = (wave >> 2) * 128;             // 0,128
  const int wc = (wave & 3) * 64;               // 0,64,128,192

  // bijective XCD swizzle
  const int nwg = gridDim.x * gridDim.y;
  int wg = blockIdx.y * gridDim.x + blockIdx.x;
  {
    const int q = nwg >> 3, r = nwg & 7;
    const int xcd = wg & 7, lo = wg >> 3;
    wg = (xcd < r ? xcd * (q + 1) : r * (q + 1) + (xcd - r) * q) + lo;
  }
  const int bm = (wg / gridDim.x) * 256, bn = (wg % gridDim.x) * 256;

  const int mrow = lane & 15;
  const int r0 = (lane >> 4) * 4;

  f32x4 acc[8][4];
  #pragma unroll
  for (int i = 0; i < 8; ++i)
    #pragma unroll
    for (int j = 0; j < 4; ++j)
      acc[i][j] = (f32x4){0.f, 0.f, 0.f, 0.f};

  // staging: load q covers rows q*64 + wave*8 + (lane>>3); row&7 == lane>>3.
  const int ssl = ((lane & 7) ^ (lane >> 3)) * 8;     // pre-swizzled global k-slice
  const int lsub = wave * 512 + lane * 8;             // linear LDS dest within q-block

  auto stage = [&](int buf, int k0){
    #pragma unroll
    for (int q = 0; q < 4; ++q){
      const int row = q * 64 + wave * 8 + (lane >> 3);
      int arow = bm + row; if (arow > M - 1) arow = M - 1;
      __builtin_amdgcn_global_load_lds(
        (const AS1 unsigned int*)(A + (size_t)arow * K + k0 + ssl),
        (AS3 unsigned int*)(Asl + buf * 16384 + q * 4096 + lsub), 16, 0, 0);
      __builtin_amdgcn_global_load_lds(
        (const AS1 unsigned int*)(BT + (size_t)(bn + row) * K + k0 + ssl),
        (AS3 unsigned int*)(Bsl + buf * 16384 + q * 4096 + lsub), 16, 0, 0);
    }
  };

  const int kslice = lane >> 4;   // 0..3
  auto compute = [&](int buf){
    #pragma unroll
    for (int ks = 0; ks < 2; ++ks){
      bf16x8 af[8], bfr[4];
      #pragma unroll
      for (int i = 0; i < 8; ++i){
        const int row = wr + i * 16 + mrow;
        const int sl = (ks * 4 + kslice) ^ (row & 7);
        af[i] = *reinterpret_cast<const bf16x8*>(&Asl[buf * 16384 + row * 64 + sl * 8]);
      }
      #pragma unroll
      for (int j = 0; j < 4; ++j){
        const int row = wc + j * 16 + mrow;
        const int sl = (ks * 4 + kslice) ^ (row & 7);
        bfr[j] = *reinterpret_cast<const bf16x8*>(&Bsl[buf * 16384 + row * 64 + sl * 8]);
      }
      #pragma unroll
      for (int i = 0; i < 8; ++i)
        #pragma unroll
        for (int j = 0; j < 4; ++j)
          acc[i][j] = __builtin_amdgcn_mfma_f32_16x16x32_bf16(af[i], bfr[j], acc[i][j], 0, 0, 0);
    }
  };

  // prologue
  stage(0, 0);
  asm volatile("s_waitcnt vmcnt(0)" ::: "memory");
  __builtin_amdgcn_s_barrier();

  const int NT = K >> 6;
  int cur = 0;
  for (int t = 0; t < NT; ++t){
    if (t + 1 < NT) stage(cur ^ 1, (t + 1) << 6);
    compute(cur);
    asm volatile("s_waitcnt vmcnt(0)" ::: "memory");
    __builtin_amdgcn_s_barrier();
    cur ^= 1;
  }

  // ---- epilogue: per-wave 16KB LDS region, two 64-row halves ----
  float* ldsF = (float*)smem;
  const int wbase = wave * 4096;                // 4096 floats = 16 KB
  const int lrow = lane >> 3, lcol = (lane & 7) * 8;
  #pragma unroll
  for (int half = 0; half < 2; ++half){
    #pragma unroll
    for (int i = 0; i < 4; ++i)
      #pragma unroll
      for (int j = 0; j < 4; ++j)
        #pragma unroll
        for (int r = 0; r < 4; ++r)
          ldsF[wbase + (i * 16 + r0 + r) * 64 + j * 16 + mrow] = acc[half * 4 + i][j][r];
    asm volatile("s_waitcnt lgkmcnt(0)" ::: "memory");
    #pragma unroll
    for (int i3 = 0; i3 < 8; ++i3){
      const int rl = i3 * 8 + lrow;
      const int row = bm + wr + half * 64 + rl;
      const int col = bn + wc + lcol;
      if (row < M){
        const f32x4 lo = *reinterpret_cast<const f32x4*>(&ldsF[wbase + rl * 64 + lcol]);
        const f32x4 hi = *reinterpret_cast<const f32x4*>(&ldsF[wbase + rl * 64 + lcol + 4]);
        const float4 b0 = ld4(bias + col), b1 = ld4(bias + col + 4);
        float v[8] = {lo[0] + b0.x, lo[1] + b0.y, lo[2] + b0.z, lo[3] + b0.w,
                      hi[0] + b1.x, hi[1] + b1.y, hi[2] + b1.z, hi[3] + b1.w};
        #pragma unroll
        for (int u = 0; u < 8; ++u){
          float t2 = v[u];
          if (ACT == 1) t2 = fmaxf(t2, 0.f);
          else if (ACT == 2) t2 = (t2 > 0.f) ? t2 : expm1f(t2);
          v[u] = t2;
        }
        if (OUTB){
          us8 ov;
          #pragma unroll
          for (int u = 0; u < 8; ++u) ov[u] = f2b(v[u]);
          *reinterpret_cast<us8*>(Cb + (size_t)row * N + col) = ov;
        } else {
          *reinterpret_cast<float4*>(Cf + (size_t)row * N + col)     = make_float4(v[0], v[1], v[2], v[3]);
          *reinterpret_cast<float4*>(Cf + (size_t)row * N + col + 4) = make_float4(v[4], v[5], v[6], v[7]);
        }
      }
    }
    asm volatile("s_waitcnt lgkmcnt(0)" ::: "memory");   // reads done before next half's writes
  }
}

// ---------------- CSR build ----------------
__global__ void count_deg(const int* __restrict__ dst, int* __restrict__ deg, int E){
  int e = blockIdx.x * blockDim.x + threadIdx.x;
  if (e < E) atomicAdd(&deg[dst[e]], 1);
}

__global__ __launch_bounds__(1024) void scan_offsets(const int* __restrict__ deg, int* __restrict__ offs, int n){
  __shared__ int ws[16];
  const int tid = threadIdx.x, lane = tid & 63, wid = tid >> 6;
  int running = 0;
  for (int base = 0; base < n; base += 1024){
    const int i = base + tid;
    const int v = (i < n) ? deg[i] : 0;
    int x = v;
    #pragma unroll
    for (int s = 1; s < 64; s <<= 1){
      int u = __shfl_up(x, s, 64);
      if (lane >= s) x += u;
    }
    if (lane == 63) ws[wid] = x;
    __syncthreads();
    if (tid < 16){
      int p = ws[tid];
      #pragma unroll
      for (int s = 1; s < 16; s <<= 1){
        int u = __shfl_up(p, s, 64);
        if (tid >= s) p += u;
      }
      ws[tid] = p;
    }
    __syncthreads();
    const int wpre = (wid > 0) ? ws[wid - 1] : 0;
    if (i < n) offs[i] = running + wpre + x - v;
    running += ws[15];
    __syncthreads();
  }
  if (tid == 0) offs[n] = running;
}

__global__ void fill_csr(const int* __restrict__ src, const int* __restrict__ dst,
                         const float* __restrict__ edge_attr,
                         const int* __restrict__ offs, int* __restrict__ cursor,
                         int* __restrict__ csr_src, float* __restrict__ csr_ea, int E){
  int e = blockIdx.x * blockDim.x + threadIdx.x;
  if (e < E){
    int d = dst[e];
    int pos = offs[d] + atomicAdd(&cursor[d], 1);
    csr_src[pos] = src[e];
    *reinterpret_cast<float4*>(csr_ea + (size_t)pos * 4) = ld4(edge_attr + (size_t)e * 4);
  }
}

// ---------------- fused GATv2 (r9 exact): block per node; 128 thr; dims [8t,8t+8); 2-edge pairs ----------------
__global__ __launch_bounds__(128) void fused_gat(
    const int* __restrict__ offs, const int* __restrict__ csr_src, const float* __restrict__ csr_ea,
    const float* __restrict__ We, const float* __restrict__ att,
    const ushort_t* __restrict__ xlr, const float* __restrict__ bias,
    ushort_t* __restrict__ out, int N)
{
  const int n = blockIdx.x;
  const int t = threadIdx.x;
  const int d0 = t * 8;

  f32x2 W0[4], W1[4], W2[4], W3[4], AT[4];
  #pragma unroll
  for (int q = 0; q < 4; ++q){
    W0[q] = *reinterpret_cast<const f32x2*>(We + d0 + 2*q);
    W1[q] = *reinterpret_cast<const f32x2*>(We + 1024 + d0 + 2*q);
    W2[q] = *reinterpret_cast<const f32x2*>(We + 2048 + d0 + 2*q);
    W3[q] = *reinterpret_cast<const f32x2*>(We + 3072 + d0 + 2*q);
    AT[q] = *reinterpret_cast<const f32x2*>(att + d0 + 2*q);
  }
  f32x2 xr[4];
  {
    const uint4 xu = *reinterpret_cast<const uint4*>(xlr + (size_t)n * 2048 + 1024 + d0);
    xr[0] = up2(xu.x); xr[1] = up2(xu.y); xr[2] = up2(xu.z); xr[3] = up2(xu.w);
  }

  const int o0 = __builtin_amdgcn_readfirstlane(offs[n]);
  const int o1 = __builtin_amdgcn_readfirstlane(offs[n + 1]);

  f32x2 acc[4];
  #pragma unroll
  for (int q = 0; q < 4; ++q) acc[q] = (f32x2){0.f, 0.f};
  float lsum = 0.f, mcur = -1e30f;

  uint4 xa = {0u,0u,0u,0u}, xb = {0u,0u,0u,0u};
  float eA0=0.f,eA1=0.f,eA2=0.f,eA3=0.f, eB0=0.f,eB1=0.f,eB2=0.f,eB3=0.f;

  auto ldedge = [&](int idx, uint4& xv, float& e0, float& e1, float& e2, float& e3){
    const int s = __builtin_amdgcn_readfirstlane(csr_src[idx]);
    xv = *reinterpret_cast<const uint4*>(xlr + (size_t)s * 2048 + d0);
    const float4 e = ld4(csr_ea + (size_t)idx * 4);
    e0 = rfl(e.x); e1 = rfl(e.y); e2 = rfl(e.z); e3 = rfl(e.w);
  };

  if (o0 < o1)     ldedge(o0,     xa, eA0,eA1,eA2,eA3);
  if (o0 + 1 < o1) ldedge(o0 + 1, xb, eB0,eB1,eB2,eB3);

  int i = o0;
  while (i < o1){
    const uint4 ca = xa; const float a0=eA0,a1=eA1,a2=eA2,a3=eA3;
    const uint4 cb = xb; const float b0=eB0,b1=eB1,b2=eB2,b3=eB3;
    const bool pair = (i + 1 < o1);
    const int ni = i + 2;
    if (ni < o1)     ldedge(ni,     xa, eA0,eA1,eA2,eA3);
    if (ni + 1 < o1) ldedge(ni + 1, xb, eB0,eB1,eB2,eB3);

    f32x2 xav[4] = {up2(ca.x), up2(ca.y), up2(ca.z), up2(ca.w)};
    f32x2 xbv[4] = {up2(cb.x), up2(cb.y), up2(cb.z), up2(cb.w)};

    f32x2 za2 = {0.f,0.f}, zb2 = {0.f,0.f};
    #pragma unroll
    for (int q = 0; q < 4; ++q){
      f32x2 ma = xav[q] + xr[q];
      ma += W0[q]*a0; ma += W1[q]*a1; ma += W2[q]*a2; ma += W3[q]*a3;
      ma = lrelu2(ma);
      za2 += ma * AT[q];
      f32x2 mb = xbv[q] + xr[q];
      mb += W0[q]*b0; mb += W1[q]*b1; mb += W2[q]*b2; mb += W3[q]*b3;
      mb = lrelu2(mb);
      zb2 += mb * AT[q];
    }
    float zA = za2[0] + za2[1];
    float zB = zb2[0] + zb2[1];
    #pragma unroll
    for (int sh = 1; sh <= 8; sh <<= 1){
      zA += __shfl_xor(zA, sh, 64);
      zB += __shfl_xor(zB, sh, 64);
    }

    if (pair){
      const float mn = fmaxf(fmaxf(mcur, zA), zB);
      const float sc = __expf(mcur - mn);
      const float pA = __expf(zA - mn);
      const float pB = __expf(zB - mn);
      lsum = lsum * sc + pA + pB;
      #pragma unroll
      for (int q = 0; q < 4; ++q)
        acc[q] = acc[q] * sc + xav[q] * pA + xbv[q] * pB;
      mcur = mn;
    } else {
      const float mn = fmaxf(mcur, zA);
      const float sc = __expf(mcur - mn);
      const float pA = __expf(zA - mn);
      lsum = lsum * sc + pA;
      #pragma unroll
      for (int q = 0; q < 4; ++q)
        acc[q] = acc[q] * sc + xav[q] * pA;
      mcur = mn;
    }
    i = ni;
  }

  const float r = 1.f / (lsum + EPSV);
  const float4 bv0 = ld4(bias + d0);
  const float4 bv1 = ld4(bias + d0 + 4);
  float o_[8] = {acc[0][0]*r + bv0.x, acc[0][1]*r + bv0.y, acc[1][0]*r + bv0.z, acc[1][1]*r + bv0.w,
                 acc[2][0]*r + bv1.x, acc[2][1]*r + bv1.y, acc[3][0]*r + bv1.z, acc[3][1]*r + bv1.w};
  us8 ov;
  #pragma unroll
  for (int j = 0; j < 8; ++j){
    float v = o_[j];
    v = (v > 0.f) ? v : expm1f(v);
    ov[j] = f2b(v);
  }
  *reinterpret_cast<us8*>(out + (size_t)n * HID + d0) = ov;
}

// ---------------- final matvec + sigmoid: one wave per row ----------------
__global__ __launch_bounds__(256) void mlp_final(const float* __restrict__ h, const float* __restrict__ w,
                                                 const float* __restrict__ b, float* __restrict__ out, int M)
{
  const int row = (int)((blockIdx.x * (size_t)blockDim.x + threadIdx.x) >> 6);
  const int lane = threadIdx.x & 63;
  if (row >= M) return;
  const float2 v  = *reinterpret_cast<const float2*>(&h[(size_t)row * 128 + lane * 2]);
  const float2 ww = *reinterpret_cast<const float2*>(&w[lane * 2]);
  float s = v.x * ww.x + v.y * ww.y;
  #pragma unroll
  for (int m = 1; m <= 32; m <<= 1) s += __shfl_xor(s, m, 64);
  if (lane == 0) out[row] = 1.f / (1.f + expf(-(s + b[0])));
}

extern "C" void kernel_launch(void* const* d_in, const int* in_sizes, int n_in,
                              void* d_out, int out_size, void* d_ws, size_t ws_size,
                              hipStream_t stream)
{
  const float* x        = (const float*)d_in[0];
  const int*   ei       = (const int*)d_in[1];
  const float* edge_attr= (const float*)d_in[2];
  const float* W_in     = (const float*)d_in[3];
  const float* b_in     = (const float*)d_in[4];
  const float* m1_W     = (const float*)d_in[5];
  const float* m1_b     = (const float*)d_in[6];
  const float* m2_W     = (const float*)d_in[7];
  const float* m2_b     = (const float*)d_in[8];
  const float* m3_W     = (const float*)d_in[9];
  const float* m3_b     = (const float*)d_in[10];
  const float* g_Wl[2]  = {(const float*)d_in[11], (const float*)d_in[18]};
  const float* g_bl[2]  = {(const float*)d_in[12], (const float*)d_in[19]};
  const float* g_Wr[2]  = {(const float*)d_in[13], (const float*)d_in[20]};
  const float* g_br[2]  = {(const float*)d_in[14], (const float*)d_in[21]};
  const float* g_We[2]  = {(const float*)d_in[15], (const float*)d_in[22]};
  const float* g_att[2] = {(const float*)d_in[16], (const float*)d_in[23]};
  const float* g_b[2]   = {(const float*)d_in[17], (const float*)d_in[24]};

  const int Nn = in_sizes[0] / 1024;
  const int E  = in_sizes[1] / 2;
  const int* srcv = ei;
  const int* dstv = ei + E;
  float* out = (float*)d_out;

  char* wsp = (char*)d_ws;
  size_t off = 0;
  auto alloc = [&](size_t bytes)->char* {
    char* p = wsp + off;
    off = (off + bytes + 255) & ~(size_t)255;
    return p;
  };
  ushort_t* hbf  = (ushort_t*)alloc((size_t)Nn * HID * 2);
  ushort_t* ubuf = (ushort_t*)alloc((size_t)Nn * HID * 2);       // x bf16, later m1 output
  ushort_t* xlr  = (ushort_t*)alloc((size_t)Nn * 2048 * 2);      // [xl | xr]
  float*    m2f  = (float*)   alloc((size_t)Nn * 128 * 4);
  ushort_t* WinT = (ushort_t*)alloc((size_t)1024 * 1024 * 2);
  ushort_t* Wlr0 = (ushort_t*)alloc((size_t)2048 * 1024 * 2);
  ushort_t* Wlr1 = (ushort_t*)alloc((size_t)2048 * 1024 * 2);
  ushort_t* m1T  = (ushort_t*)alloc((size_t)512 * 1024 * 2);
  ushort_t* m2T  = (ushort_t*)alloc((size_t)128 * 512 * 2);
  float*  biasc  = (float*)   alloc((size_t)2048 * 2 * 4);
  int* deg    = (int*)alloc((size_t)Nn * 2 * 4);
  int* cursor = deg + Nn;
  int* offs   = (int*)alloc((size_t)(Nn + 1) * 4);
  int* csr_src= (int*)alloc((size_t)E * 4);
  float* csr_ea = (float*)alloc((size_t)E * 4 * 4);
  ushort_t* Wlr[2]  = {Wlr0, Wlr1};
  float*    blr[2]  = {biasc, biasc + 2048};

  // --- weight prep ---
  TP5 tp;
  tp.src[0] = W_in;    tp.dst[0] = WinT;
  tp.src[1] = g_Wl[0]; tp.dst[1] = Wlr0;
  tp.src[2] = g_Wr[0]; tp.dst[2] = Wlr0 + 1024*1024;
  tp.src[3] = g_Wl[1]; tp.dst[3] = Wlr1;
  tp.src[4] = g_Wr[1]; tp.dst[4] = Wlr1 + 1024*1024;
  transpose_f2b_5<<<dim3(32, 32, 5), 256, 0, stream>>>(tp);
  transpose_f2b<<<dim3(16, 32), 256, 0, stream>>>(m1_W, m1T, 1024, 512);
  transpose_f2b<<<dim3(4, 16), 256, 0, stream>>>(m2_W, m2T, 512, 128);
  convert_f2b<<<2048, 256, 0, stream>>>(x, ubuf, (size_t)Nn * HID);
  BC4 bc; bc.s[0] = g_bl[0]; bc.s[1] = g_br[0]; bc.s[2] = g_bl[1]; bc.s[3] = g_br[1];
  concat_bias<<<16, 256, 0, stream>>>(bc, biasc);

  // --- CSR by dst ---
  hipMemsetAsync(deg, 0, (size_t)Nn * 2 * 4, stream);
  count_deg<<<(E + 255)/256, 256, 0, stream>>>(dstv, deg, E);
  scan_offsets<<<1, 1024, 0, stream>>>(deg, offs, Nn);
  fill_csr<<<(E + 255)/256, 256, 0, stream>>>(srcv, dstv, edge_attr, offs, cursor, csr_src, csr_ea, E);

  const int MB = (Nn + 127) / 128;
  const int MB2 = (Nn + 255) / 256;
  // h0 = elu(x @ W_in + b_in) -> hbf (bf16)
  gemm_mfma<2, 1><<<dim3(8, MB), 512, 0, stream>>>(ubuf, WinT, b_in, nullptr, hbf, Nn, 1024, 1024);

  for (int L = 0; L < 2; ++L){
    gemm_mfma256<0, 1><<<dim3(8, MB2), 512, 0, stream>>>(hbf, Wlr[L], blr[L], nullptr, xlr, Nn, 1024, 2048);
    fused_gat<<<Nn, 128, 0, stream>>>(offs, csr_src, csr_ea, g_We[L], g_att[L], xlr, g_b[L], hbf, Nn);
  }

  // MLP
  gemm_mfma<1, 1><<<dim3(4, MB), 512, 0, stream>>>(hbf, m1T, m1_b, nullptr, ubuf, Nn, 1024, 512);
  gemm_mfma<1, 0><<<dim3(1, MB), 512, 0, stream>>>(ubuf, m2T, m2_b, m2f, nullptr, Nn, 512, 128);
  mlp_final<<<((size_t)Nn * 64 + 255)/256, 256, 0, stream>>>(m2f, m3_W, m3_b, out, Nn);
}

// Round 13
// 336.605 us; speedup vs baseline: 1.1026x; 1.1026x over previous
//
#include <hip/hip_runtime.h>
#include <math.h>

constexpr int HID = 1024;
constexpr float NEG_SLOPE = 0.2f;
constexpr float EPSV = 1e-16f;

typedef __bf16 bf16x8 __attribute__((ext_vector_type(8)));
typedef float f32x4 __attribute__((ext_vector_type(4)));
typedef float f32x2 __attribute__((ext_vector_type(2)));
typedef unsigned short us8 __attribute__((ext_vector_type(8)));
typedef unsigned short us4 __attribute__((ext_vector_type(4)));
typedef unsigned short ushort_t;

#define AS1 __attribute__((address_space(1)))
#define AS3 __attribute__((address_space(3)))

__device__ __forceinline__ float4 ld4(const float* p){ return *reinterpret_cast<const float4*>(p); }
__device__ __forceinline__ float b2f(ushort_t u){ return __uint_as_float(((unsigned)u) << 16); }
__device__ __forceinline__ ushort_t f2b(float f){
  unsigned u = __float_as_uint(f);
  return (ushort_t)((u + 0x7FFFu + ((u >> 16) & 1u)) >> 16);
}
__device__ __forceinline__ float rfl(float x){
  return __uint_as_float(__builtin_amdgcn_readfirstlane(__float_as_uint(x)));
}
__device__ __forceinline__ f32x2 up2(unsigned u){
  f32x2 r;
  r[0] = __uint_as_float(u << 16);
  r[1] = __uint_as_float(u & 0xffff0000u);
  return r;
}
__device__ __forceinline__ f32x2 lrelu2(f32x2 v){
  return __builtin_elementwise_max(v, v * NEG_SLOPE);
}

// ---------------- batched weight transpose + f32->bf16 (five 1024x1024 mats) ----------------
struct TP5 { const float* src[5]; ushort_t* dst[5]; };
__global__ __launch_bounds__(256) void transpose_f2b_5(TP5 p){
  const int z = blockIdx.z;
  const float* W = p.src[z];
  ushort_t* WT = p.dst[z];
  __shared__ float tile[32][33];
  const int tx = threadIdx.x & 31, ty = threadIdx.x >> 5;
  const int n0 = blockIdx.x * 32, k0 = blockIdx.y * 32;
  #pragma unroll
  for (int r = 0; r < 32; r += 8)
    tile[ty + r][tx] = W[(size_t)(k0 + ty + r) * 1024 + n0 + tx];
  __syncthreads();
  #pragma unroll
  for (int r = 0; r < 32; r += 8)
    WT[(size_t)(n0 + ty + r) * 1024 + k0 + tx] = f2b(tile[tx][ty + r]);
}

// ---------------- single transpose (for m1/m2) ----------------
__global__ __launch_bounds__(256) void transpose_f2b(const float* __restrict__ W, ushort_t* __restrict__ WT,
                                                     int K, int N){
  __shared__ float tile[32][33];
  const int tx = threadIdx.x & 31, ty = threadIdx.x >> 5;
  const int n0 = blockIdx.x * 32, k0 = blockIdx.y * 32;
  #pragma unroll
  for (int r = 0; r < 32; r += 8)
    tile[ty + r][tx] = W[(size_t)(k0 + ty + r) * N + n0 + tx];
  __syncthreads();
  #pragma unroll
  for (int r = 0; r < 32; r += 8)
    WT[(size_t)(n0 + ty + r) * K + k0 + tx] = f2b(tile[tx][ty + r]);
}

// ---------------- bias concat (4 x 1024 f32) ----------------
struct BC4 { const float* s[4]; };
__global__ void concat_bias(BC4 p, float* __restrict__ dst){
  const int i = blockIdx.x * blockDim.x + threadIdx.x;   // 4096 total
  dst[i] = p.s[i >> 10][i & 1023];
}

// ---------------- f32 -> bf16 elementwise ----------------
__global__ void convert_f2b(const float* __restrict__ in, ushort_t* __restrict__ out, size_t n){
  size_t i = ((size_t)blockIdx.x * blockDim.x + threadIdx.x) * 4;
  const size_t stride = (size_t)gridDim.x * blockDim.x * 4;
  for (; i < n; i += stride){
    const float4 v = ld4(in + i);
    us4 o = {f2b(v.x), f2b(v.y), f2b(v.z), f2b(v.w)};
    *reinterpret_cast<us4*>(out + i) = o;
  }
}

// ---------------- bf16 MFMA GEMM, 128x128 tile, BK=64, 8 waves (32x64 each) ----------------
// r9 structure + T4 counted-vmcnt: both LDS buffers staged ahead; per-iter wait is
// vmcnt(4) (own buf's loads) instead of a full drain; re-stage consumed buf for t+2.
template<int ACT, int OUTB>
__global__ __launch_bounds__(512, 4) void gemm_mfma(
    const ushort_t* __restrict__ A, const ushort_t* __restrict__ BT,
    const float* __restrict__ bias, float* __restrict__ Cf, ushort_t* __restrict__ Cb,
    int M, int K, int N)
{
  __shared__ __align__(16) char smem[65536];
  ushort_t* Asl = (ushort_t*)smem;
  ushort_t* Bsl = (ushort_t*)(smem + 32768);
  const int tid = threadIdx.x;
  const int lane = tid & 63, wave = tid >> 6;
  const int wr = (wave >> 1) * 32;
  const int wc = (wave & 1) * 64;

  const int nwg = gridDim.x * gridDim.y;
  int wg = blockIdx.y * gridDim.x + blockIdx.x;
  {
    const int q = nwg >> 3, r = nwg & 7;
    const int xcd = wg & 7, lo = wg >> 3;
    wg = (xcd < r ? xcd * (q + 1) : r * (q + 1) + (xcd - r) * q) + lo;
  }
  const int bm = (wg / gridDim.x) * 128, bn = (wg % gridDim.x) * 128;

  const int mrow = lane & 15;
  const int r0 = (lane >> 4) * 4;

  f32x4 acc[2][4];
  #pragma unroll
  for (int i = 0; i < 2; ++i)
    #pragma unroll
    for (int j = 0; j < 4; ++j)
      acc[i][j] = (f32x4){0.f, 0.f, 0.f, 0.f};

  // staging map: LDS slot (row, kslice=lane&7) <- global (row, kslice ^ (row&7)).
  const int srow = tid >> 3;
  const int ssl = (((lane & 7) ^ (lane >> 3))) * 8;   // pre-swizzled global k-slice
  const int ldst = wave * 512 + lane * 8;             // linear LDS dest

  auto stage = [&](int buf, int k0){
    #pragma unroll
    for (int q = 0; q < 2; ++q){
      const int row = q * 64 + srow;
      int arow = bm + row; if (arow > M - 1) arow = M - 1;
      __builtin_amdgcn_global_load_lds(
        (const AS1 unsigned int*)(A + (size_t)arow * K + k0 + ssl),
        (AS3 unsigned int*)(Asl + buf * 8192 + q * 4096 + ldst), 16, 0, 0);
      __builtin_amdgcn_global_load_lds(
        (const AS1 unsigned int*)(BT + (size_t)(bn + row) * K + k0 + ssl),
        (AS3 unsigned int*)(Bsl + buf * 8192 + q * 4096 + ldst), 16, 0, 0);
    }
  };

  const int kslice = (lane >> 4);
  auto compute = [&](int buf){
    #pragma unroll
    for (int ks = 0; ks < 2; ++ks){
      bf16x8 af[2], bfr[4];
      #pragma unroll
      for (int i = 0; i < 2; ++i){
        const int row = wr + i * 16 + mrow;
        const int sl = (ks * 4 + kslice) ^ (row & 7);
        af[i] = *reinterpret_cast<const bf16x8*>(&Asl[buf * 8192 + row * 64 + sl * 8]);
      }
      #pragma unroll
      for (int j = 0; j < 4; ++j){
        const int row = wc + j * 16 + mrow;
        const int sl = (ks * 4 + kslice) ^ (row & 7);
        bfr[j] = *reinterpret_cast<const bf16x8*>(&Bsl[buf * 8192 + row * 64 + sl * 8]);
      }
      #pragma unroll
      for (int i = 0; i < 2; ++i)
        #pragma unroll
        for (int j = 0; j < 4; ++j)
          acc[i][j] = __builtin_amdgcn_mfma_f32_16x16x32_bf16(af[i], bfr[j], acc[i][j], 0, 0, 0);
    }
  };

  const int NT = K >> 6;
  // prologue: both buffers in flight (8 loads/wave outstanding)
  stage(0, 0);
  if (NT > 1) stage(1, 64);

  int cur = 0;
  for (int t = 0; t < NT; ++t){
    if (t + 1 < NT) asm volatile("s_waitcnt vmcnt(4)" ::: "memory");  // own buf[cur] landed
    else            asm volatile("s_waitcnt vmcnt(0)" ::: "memory");  // final tile: drain
    __builtin_amdgcn_s_barrier();            // all waves' buf[cur] loads published
    compute(cur);                            // LDS reads complete in-order before last MFMA
    __builtin_amdgcn_s_barrier();            // all waves done reading buf[cur]
    if (t + 2 < NT) stage(cur, (t + 2) << 6); // WAR-safe: re-stage consumed buffer
    cur ^= 1;
  }

  // ---- epilogue: repack via per-wave LDS region -> coalesced 16B stores ----
  float* ldsF = (float*)smem;
  const int wbase = wave * 2048;
  #pragma unroll
  for (int i = 0; i < 2; ++i)
    #pragma unroll
    for (int j = 0; j < 4; ++j)
      #pragma unroll
      for (int r = 0; r < 4; ++r)
        ldsF[wbase + (i * 16 + r0 + r) * 64 + j * 16 + mrow] = acc[i][j][r];
  asm volatile("s_waitcnt lgkmcnt(0)" ::: "memory");

  const int lrow = lane >> 3, lcol = (lane & 7) * 8;
  #pragma unroll
  for (int i2 = 0; i2 < 4; ++i2){
    const int row = bm + wr + i2 * 8 + lrow;
    const int col = bn + wc + lcol;
    if (row < M){
      const f32x4 lo = *reinterpret_cast<const f32x4*>(&ldsF[wbase + (i2 * 8 + lrow) * 64 + lcol]);
      const f32x4 hi = *reinterpret_cast<const f32x4*>(&ldsF[wbase + (i2 * 8 + lrow) * 64 + lcol + 4]);
      const float4 b0 = ld4(bias + col), b1 = ld4(bias + col + 4);
      float v[8] = {lo[0] + b0.x, lo[1] + b0.y, lo[2] + b0.z, lo[3] + b0.w,
                    hi[0] + b1.x, hi[1] + b1.y, hi[2] + b1.z, hi[3] + b1.w};
      #pragma unroll
      for (int u = 0; u < 8; ++u){
        float t2 = v[u];
        if (ACT == 1) t2 = fmaxf(t2, 0.f);
        else if (ACT == 2) t2 = (t2 > 0.f) ? t2 : expm1f(t2);
        v[u] = t2;
      }
      if (OUTB){
        us8 ov;
        #pragma unroll
        for (int u = 0; u < 8; ++u) ov[u] = f2b(v[u]);
        *reinterpret_cast<us8*>(Cb + (size_t)row * N + col) = ov;
      } else {
        *reinterpret_cast<float4*>(Cf + (size_t)row * N + col)     = make_float4(v[0], v[1], v[2], v[3]);
        *reinterpret_cast<float4*>(Cf + (size_t)row * N + col + 4) = make_float4(v[4], v[5], v[6], v[7]);
      }
    }
  }
}

// ---------------- CSR build ----------------
__global__ void count_deg(const int* __restrict__ dst, int* __restrict__ deg, int E){
  int e = blockIdx.x * blockDim.x + threadIdx.x;
  if (e < E) atomicAdd(&deg[dst[e]], 1);
}

__global__ __launch_bounds__(1024) void scan_offsets(const int* __restrict__ deg, int* __restrict__ offs, int n){
  __shared__ int ws[16];
  const int tid = threadIdx.x, lane = tid & 63, wid = tid >> 6;
  int running = 0;
  for (int base = 0; base < n; base += 1024){
    const int i = base + tid;
    const int v = (i < n) ? deg[i] : 0;
    int x = v;
    #pragma unroll
    for (int s = 1; s < 64; s <<= 1){
      int u = __shfl_up(x, s, 64);
      if (lane >= s) x += u;
    }
    if (lane == 63) ws[wid] = x;
    __syncthreads();
    if (tid < 16){
      int p = ws[tid];
      #pragma unroll
      for (int s = 1; s < 16; s <<= 1){
        int u = __shfl_up(p, s, 64);
        if (tid >= s) p += u;
      }
      ws[tid] = p;
    }
    __syncthreads();
    const int wpre = (wid > 0) ? ws[wid - 1] : 0;
    if (i < n) offs[i] = running + wpre + x - v;
    running += ws[15];
    __syncthreads();
  }
  if (tid == 0) offs[n] = running;
}

__global__ void fill_csr(const int* __restrict__ src, const int* __restrict__ dst,
                         const float* __restrict__ edge_attr,
                         const int* __restrict__ offs, int* __restrict__ cursor,
                         int* __restrict__ csr_src, float* __restrict__ csr_ea, int E){
  int e = blockIdx.x * blockDim.x + threadIdx.x;
  if (e < E){
    int d = dst[e];
    int pos = offs[d] + atomicAdd(&cursor[d], 1);
    csr_src[pos] = src[e];
    *reinterpret_cast<float4*>(csr_ea + (size_t)pos * 4) = ld4(edge_attr + (size_t)e * 4);
  }
}

// ---------------- fused GATv2 (r9 exact): block per node; 128 thr; dims [8t,8t+8); 2-edge pairs ----------------
__global__ __launch_bounds__(128) void fused_gat(
    const int* __restrict__ offs, const int* __restrict__ csr_src, const float* __restrict__ csr_ea,
    const float* __restrict__ We, const float* __restrict__ att,
    const ushort_t* __restrict__ xlr, const float* __restrict__ bias,
    ushort_t* __restrict__ out, int N)
{
  const int n = blockIdx.x;
  const int t = threadIdx.x;
  const int d0 = t * 8;

  f32x2 W0[4], W1[4], W2[4], W3[4], AT[4];
  #pragma unroll
  for (int q = 0; q < 4; ++q){
    W0[q] = *reinterpret_cast<const f32x2*>(We + d0 + 2*q);
    W1[q] = *reinterpret_cast<const f32x2*>(We + 1024 + d0 + 2*q);
    W2[q] = *reinterpret_cast<const f32x2*>(We + 2048 + d0 + 2*q);
    W3[q] = *reinterpret_cast<const f32x2*>(We + 3072 + d0 + 2*q);
    AT[q] = *reinterpret_cast<const f32x2*>(att + d0 + 2*q);
  }
  f32x2 xr[4];
  {
    const uint4 xu = *reinterpret_cast<const uint4*>(xlr + (size_t)n * 2048 + 1024 + d0);
    xr[0] = up2(xu.x); xr[1] = up2(xu.y); xr[2] = up2(xu.z); xr[3] = up2(xu.w);
  }

  const int o0 = __builtin_amdgcn_readfirstlane(offs[n]);
  const int o1 = __builtin_amdgcn_readfirstlane(offs[n + 1]);

  f32x2 acc[4];
  #pragma unroll
  for (int q = 0; q < 4; ++q) acc[q] = (f32x2){0.f, 0.f};
  float lsum = 0.f, mcur = -1e30f;

  uint4 xa = {0u,0u,0u,0u}, xb = {0u,0u,0u,0u};
  float eA0=0.f,eA1=0.f,eA2=0.f,eA3=0.f, eB0=0.f,eB1=0.f,eB2=0.f,eB3=0.f;

  auto ldedge = [&](int idx, uint4& xv, float& e0, float& e1, float& e2, float& e3){
    const int s = __builtin_amdgcn_readfirstlane(csr_src[idx]);
    xv = *reinterpret_cast<const uint4*>(xlr + (size_t)s * 2048 + d0);
    const float4 e = ld4(csr_ea + (size_t)idx * 4);
    e0 = rfl(e.x); e1 = rfl(e.y); e2 = rfl(e.z); e3 = rfl(e.w);
  };

  if (o0 < o1)     ldedge(o0,     xa, eA0,eA1,eA2,eA3);
  if (o0 + 1 < o1) ldedge(o0 + 1, xb, eB0,eB1,eB2,eB3);

  int i = o0;
  while (i < o1){
    const uint4 ca = xa; const float a0=eA0,a1=eA1,a2=eA2,a3=eA3;
    const uint4 cb = xb; const float b0=eB0,b1=eB1,b2=eB2,b3=eB3;
    const bool pair = (i + 1 < o1);
    const int ni = i + 2;
    if (ni < o1)     ldedge(ni,     xa, eA0,eA1,eA2,eA3);
    if (ni + 1 < o1) ldedge(ni + 1, xb, eB0,eB1,eB2,eB3);

    f32x2 xav[4] = {up2(ca.x), up2(ca.y), up2(ca.z), up2(ca.w)};
    f32x2 xbv[4] = {up2(cb.x), up2(cb.y), up2(cb.z), up2(cb.w)};

    f32x2 za2 = {0.f,0.f}, zb2 = {0.f,0.f};
    #pragma unroll
    for (int q = 0; q < 4; ++q){
      f32x2 ma = xav[q] + xr[q];
      ma += W0[q]*a0; ma += W1[q]*a1; ma += W2[q]*a2; ma += W3[q]*a3;
      ma = lrelu2(ma);
      za2 += ma * AT[q];
      f32x2 mb = xbv[q] + xr[q];
      mb += W0[q]*b0; mb += W1[q]*b1; mb += W2[q]*b2; mb += W3[q]*b3;
      mb = lrelu2(mb);
      zb2 += mb * AT[q];
    }
    float zA = za2[0] + za2[1];
    float zB = zb2[0] + zb2[1];
    #pragma unroll
    for (int sh = 1; sh <= 8; sh <<= 1){
      zA += __shfl_xor(zA, sh, 64);
      zB += __shfl_xor(zB, sh, 64);
    }

    if (pair){
      const float mn = fmaxf(fmaxf(mcur, zA), zB);
      const float sc = __expf(mcur - mn);
      const float pA = __expf(zA - mn);
      const float pB = __expf(zB - mn);
      lsum = lsum * sc + pA + pB;
      #pragma unroll
      for (int q = 0; q < 4; ++q)
        acc[q] = acc[q] * sc + xav[q] * pA + xbv[q] * pB;
      mcur = mn;
    } else {
      const float mn = fmaxf(mcur, zA);
      const float sc = __expf(mcur - mn);
      const float pA = __expf(zA - mn);
      lsum = lsum * sc + pA;
      #pragma unroll
      for (int q = 0; q < 4; ++q)
        acc[q] = acc[q] * sc + xav[q] * pA;
      mcur = mn;
    }
    i = ni;
  }

  const float r = 1.f / (lsum + EPSV);
  const float4 bv0 = ld4(bias + d0);
  const float4 bv1 = ld4(bias + d0 + 4);
  float o_[8] = {acc[0][0]*r + bv0.x, acc[0][1]*r + bv0.y, acc[1][0]*r + bv0.z, acc[1][1]*r + bv0.w,
                 acc[2][0]*r + bv1.x, acc[2][1]*r + bv1.y, acc[3][0]*r + bv1.z, acc[3][1]*r + bv1.w};
  us8 ov;
  #pragma unroll
  for (int j = 0; j < 8; ++j){
    float v = o_[j];
    v = (v > 0.f) ? v : expm1f(v);
    ov[j] = f2b(v);
  }
  *reinterpret_cast<us8*>(out + (size_t)n * HID + d0) = ov;
}

// ---------------- final matvec + sigmoid: one wave per row ----------------
__global__ __launch_bounds__(256) void mlp_final(const float* __restrict__ h, const float* __restrict__ w,
                                                 const float* __restrict__ b, float* __restrict__ out, int M)
{
  const int row = (int)((blockIdx.x * (size_t)blockDim.x + threadIdx.x) >> 6);
  const int lane = threadIdx.x & 63;
  if (row >= M) return;
  const float2 v  = *reinterpret_cast<const float2*>(&h[(size_t)row * 128 + lane * 2]);
  const float2 ww = *reinterpret_cast<const float2*>(&w[lane * 2]);
  float s = v.x * ww.x + v.y * ww.y;
  #pragma unroll
  for (int m = 1; m <= 32; m <<= 1) s += __shfl_xor(s, m, 64);
  if (lane == 0) out[row] = 1.f / (1.f + expf(-(s + b[0])));
}

extern "C" void kernel_launch(void* const* d_in, const int* in_sizes, int n_in,
                              void* d_out, int out_size, void* d_ws, size_t ws_size,
                              hipStream_t stream)
{
  const float* x        = (const float*)d_in[0];
  const int*   ei       = (const int*)d_in[1];
  const float* edge_attr= (const float*)d_in[2];
  const float* W_in     = (const float*)d_in[3];
  const float* b_in     = (const float*)d_in[4];
  const float* m1_W     = (const float*)d_in[5];
  const float* m1_b     = (const float*)d_in[6];
  const float* m2_W     = (const float*)d_in[7];
  const float* m2_b     = (const float*)d_in[8];
  const float* m3_W     = (const float*)d_in[9];
  const float* m3_b     = (const float*)d_in[10];
  const float* g_Wl[2]  = {(const float*)d_in[11], (const float*)d_in[18]};
  const float* g_bl[2]  = {(const float*)d_in[12], (const float*)d_in[19]};
  const float* g_Wr[2]  = {(const float*)d_in[13], (const float*)d_in[20]};
  const float* g_br[2]  = {(const float*)d_in[14], (const float*)d_in[21]};
  const float* g_We[2]  = {(const float*)d_in[15], (const float*)d_in[22]};
  const float* g_att[2] = {(const float*)d_in[16], (const float*)d_in[23]};
  const float* g_b[2]   = {(const float*)d_in[17], (const float*)d_in[24]};

  const int Nn = in_sizes[0] / 1024;
  const int E  = in_sizes[1] / 2;
  const int* srcv = ei;
  const int* dstv = ei + E;
  float* out = (float*)d_out;

  char* wsp = (char*)d_ws;
  size_t off = 0;
  auto alloc = [&](size_t bytes)->char* {
    char* p = wsp + off;
    off = (off + bytes + 255) & ~(size_t)255;
    return p;
  };
  ushort_t* hbf  = (ushort_t*)alloc((size_t)Nn * HID * 2);
  ushort_t* ubuf = (ushort_t*)alloc((size_t)Nn * HID * 2);       // x bf16, later m1 output
  ushort_t* xlr  = (ushort_t*)alloc((size_t)Nn * 2048 * 2);      // [xl | xr]
  float*    m2f  = (float*)   alloc((size_t)Nn * 128 * 4);
  ushort_t* WinT = (ushort_t*)alloc((size_t)1024 * 1024 * 2);
  ushort_t* Wlr0 = (ushort_t*)alloc((size_t)2048 * 1024 * 2);
  ushort_t* Wlr1 = (ushort_t*)alloc((size_t)2048 * 1024 * 2);
  ushort_t* m1T  = (ushort_t*)alloc((size_t)512 * 1024 * 2);
  ushort_t* m2T  = (ushort_t*)alloc((size_t)128 * 512 * 2);
  float*  biasc  = (float*)   alloc((size_t)2048 * 2 * 4);
  int* deg    = (int*)alloc((size_t)Nn * 2 * 4);
  int* cursor = deg + Nn;
  int* offs   = (int*)alloc((size_t)(Nn + 1) * 4);
  int* csr_src= (int*)alloc((size_t)E * 4);
  float* csr_ea = (float*)alloc((size_t)E * 4 * 4);
  ushort_t* Wlr[2]  = {Wlr0, Wlr1};
  float*    blr[2]  = {biasc, biasc + 2048};

  // --- weight prep ---
  TP5 tp;
  tp.src[0] = W_in;    tp.dst[0] = WinT;
  tp.src[1] = g_Wl[0]; tp.dst[1] = Wlr0;
  tp.src[2] = g_Wr[0]; tp.dst[2] = Wlr0 + 1024*1024;
  tp.src[3] = g_Wl[1]; tp.dst[3] = Wlr1;
  tp.src[4] = g_Wr[1]; tp.dst[4] = Wlr1 + 1024*1024;
  transpose_f2b_5<<<dim3(32, 32, 5), 256, 0, stream>>>(tp);
  transpose_f2b<<<dim3(16, 32), 256, 0, stream>>>(m1_W, m1T, 1024, 512);
  transpose_f2b<<<dim3(4, 16), 256, 0, stream>>>(m2_W, m2T, 512, 128);
  convert_f2b<<<2048, 256, 0, stream>>>(x, ubuf, (size_t)Nn * HID);
  BC4 bc; bc.s[0] = g_bl[0]; bc.s[1] = g_br[0]; bc.s[2] = g_bl[1]; bc.s[3] = g_br[1];
  concat_bias<<<16, 256, 0, stream>>>(bc, biasc);

  // --- CSR by dst ---
  hipMemsetAsync(deg, 0, (size_t)Nn * 2 * 4, stream);
  count_deg<<<(E + 255)/256, 256, 0, stream>>>(dstv, deg, E);
  scan_offsets<<<1, 1024, 0, stream>>>(deg, offs, Nn);
  fill_csr<<<(E + 255)/256, 256, 0, stream>>>(srcv, dstv, edge_attr, offs, cursor, csr_src, csr_ea, E);

  const int MB = (Nn + 127) / 128;
  // h0 = elu(x @ W_in + b_in) -> hbf (bf16)
  gemm_mfma<2, 1><<<dim3(8, MB), 512, 0, stream>>>(ubuf, WinT, b_in, nullptr, hbf, Nn, 1024, 1024);

  for (int L = 0; L < 2; ++L){
    gemm_mfma<0, 1><<<dim3(16, MB), 512, 0, stream>>>(hbf, Wlr[L], blr[L], nullptr, xlr, Nn, 1024, 2048);
    fused_gat<<<Nn, 128, 0, stream>>>(offs, csr_src, csr_ea, g_We[L], g_att[L], xlr, g_b[L], hbf, Nn);
  }

  // MLP
  gemm_mfma<1, 1><<<dim3(4, MB), 512, 0, stream>>>(hbf, m1T, m1_b, nullptr, ubuf, Nn, 1024, 512);
  gemm_mfma<1, 0><<<dim3(1, MB), 512, 0, stream>>>(ubuf, m2T, m2_b, m2f, nullptr, Nn, 512, 128);
  mlp_final<<<((size_t)Nn * 64 + 255)/256, 256, 0, stream>>>(m2f, m3_W, m3_b, out, Nn);
}